// Round 3
// baseline (278.452 us; speedup 1.0000x reference)
//
#include <hip/hip_runtime.h>
#include <math.h>

#define NDET 4096
#define DIM  128
#define HID  64
#define NOSC 28
#define KDIM 56   // 28 cos + 28 sin

constexpr float TWO_PI_F = 6.28318530717958647692f;

__device__ __forceinline__ unsigned f2sort(float f){
    unsigned u = __float_as_uint(f);
    return (u & 0x80000000u) ? ~u : (u | 0x80000000u);
}
__device__ __forceinline__ float sort2f(unsigned u){
    return __uint_as_float((u & 0x80000000u) ? (u & 0x7fffffffu) : ~u);
}
// broadcast lane t's value to all lanes (VALU pipe, no LDS)
__device__ __forceinline__ float lane_bcast(float v, int t){
    return __uint_as_float(__builtin_amdgcn_readlane(__float_as_uint(v), t));
}

// ---------------------------------------------------------------------------
// Encode: 2 rows per 64-lane wave, 4 waves/block, 1024 blocks (16 waves/CU).
// x via wave-uniform scalar loads; phase+amp nets fused in one d-loop (shared
// x loads, 4 independent FMA chains). Oscillators packed: lanes 0..31 = row0,
// lanes 32..63 = row1. Blocks 0..511 -> t (evolve, At); 512..1023 -> t1 (Bt).
// Outputs K-major: At[k][i], k: 0..27 cos, 28..55 sin.
// ---------------------------------------------------------------------------
__global__ __launch_bounds__(256) void encode_kernel(
    const float* __restrict__ det_t, const float* __restrict__ det_t1,
    const float* __restrict__ Wp1, const float* __restrict__ bp1,
    const float* __restrict__ Wp2, const float* __restrict__ bp2,
    const float* __restrict__ Wa1, const float* __restrict__ ba1,
    const float* __restrict__ Wa2, const float* __restrict__ ba2,
    float* __restrict__ At, float* __restrict__ Bt)
{
    const int tid  = threadIdx.x;
    const int lane = tid & 63;
    const int wv   = tid >> 6;
    const int b    = blockIdx.x;
    const bool isT = b < 512;
    const int lr = __builtin_amdgcn_readfirstlane(((b & 511) << 3) + wv * 2);
    const float* __restrict__ src = (isT ? det_t : det_t1) + (size_t)lr * DIM;

    // ---- layer 1: phase (+amp for t rows), fused over d ----
    float h0 = bp1[lane], h1 = h0;
    float g0 = 0.0f, g1 = 0.0f;
    if (isT){
        g0 = ba1[lane]; g1 = g0;
        #pragma unroll 8
        for (int d = 0; d < DIM; ++d){
            float x0 = src[d], x1 = src[DIM + d];   // wave-uniform -> s_load
            float wp = Wp1[d * HID + lane];
            float wa = Wa1[d * HID + lane];
            h0 = fmaf(x0, wp, h0);  h1 = fmaf(x1, wp, h1);
            g0 = fmaf(x0, wa, g0);  g1 = fmaf(x1, wa, g1);
        }
        g0 = fmaxf(g0, 0.0f); g1 = fmaxf(g1, 0.0f);
    } else {
        #pragma unroll 8
        for (int d = 0; d < DIM; ++d){
            float x0 = src[d], x1 = src[DIM + d];
            float wp = Wp1[d * HID + lane];
            h0 = fmaf(x0, wp, h0);  h1 = fmaf(x1, wp, h1);
        }
    }
    h0 = fmaxf(h0, 0.0f); h1 = fmaxf(h1, 0.0f);

    // ---- layer 2: oscillator k = lane&31 (valid < 28); both rows parallel ----
    const int k  = lane & 31;
    const bool kv = k < NOSC;
    const int kc = kv ? k : 0;

    float pa = bp2[kc], pb = pa;
    #pragma unroll 16
    for (int t = 0; t < HID; ++t){
        float w2 = Wp2[t * NOSC + kc];          // 7KB, L1-hot
        pa = fmaf(lane_bcast(h0, t), w2, pa);
        pb = fmaf(lane_bcast(h1, t), w2, pb);
    }
    float aa = 0.0f, ab = 0.0f;
    if (isT){
        aa = ba2[kc]; ab = aa;
        #pragma unroll 16
        for (int t = 0; t < HID; ++t){
            float w2 = Wa2[t * NOSC + kc];
            aa = fmaf(lane_bcast(g0, t), w2, aa);
            ab = fmaf(lane_bcast(g1, t), w2, ab);
        }
    }

    const bool hiHalf = lane >= 32;
    float p2 = hiHalf ? pb : pa;
    float ph = fmodf(p2, TWO_PI_F);
    if (ph < 0.0f) ph += TWO_PI_F;               // python-style mod, [0, 2pi)

    // ---- Kuramoto evolve (t rows only); butterfly within each 32-lane half ----
    if (isT){
        float a2 = hiHalf ? ab : aa;
        float am = fmaxf(a2, 0.0f) + log1pf(expf(-fabsf(a2)));   // stable softplus
        const float omega = TWO_PI_F * ((k < 4) ? 2.0f : (k < 12) ? 6.0f : 40.0f);
        for (int s5 = 0; s5 < 5; ++s5){
            float sn, cs;
            sincosf(ph, &sn, &cs);
            float c = kv ? cs : 0.0f;
            float s = kv ? sn : 0.0f;
            float sc = c, ss = s;
            sc += __shfl_xor(sc, 16); ss += __shfl_xor(ss, 16);
            sc += __shfl_xor(sc,  8); ss += __shfl_xor(ss,  8);
            sc += __shfl_xor(sc,  4); ss += __shfl_xor(ss,  4);
            sc += __shfl_xor(sc,  2); ss += __shfl_xor(ss,  2);
            sc += __shfl_xor(sc,  1); ss += __shfl_xor(ss,  1);
            float mc = sc * (1.0f / NOSC);
            float ms = ss * (1.0f / NOSC);
            float coupling = ms * c - mc * s;
            ph += 0.01f * (omega + am * coupling);
            ph = fmodf(ph, TWO_PI_F);
            if (ph < 0.0f) ph += TWO_PI_F;
        }
    }

    if (kv){
        const int row = lr + (hiHalf ? 1 : 0);
        float sn, cs;
        sincosf(ph, &sn, &cs);
        float* __restrict__ dst = isT ? At : Bt;
        dst[k * NDET + row]          = cs;
        dst[(NOSC + k) * NDET + row] = sn;
    }
}

// ---------------------------------------------------------------------------
// Sim GEMM: 128x128 tile / block, 256 threads, 8x8 micro-tile, K in 2x28
// chunks (28.7KB LDS). Explicit 1-ahead software pipeline: ds_read frag kk+1
// while FMAing frag kk. __launch_bounds__(256,4): VGPR cap 128 -> acc in
// plain VGPRs, 4 blocks/CU. Fused per-row argmax -> atomicMax packed key.
// ---------------------------------------------------------------------------
__global__ __launch_bounds__(256, 4) void sim_kernel(
    const float* __restrict__ At, const float* __restrict__ Bt,
    float* __restrict__ sim_out, unsigned long long* __restrict__ rowmax)
{
    __shared__ float As[28][128];
    __shared__ float Bs[28][128];

    const int tid  = threadIdx.x;
    const int lane = tid & 63;
    const int wid  = tid >> 6;
    const int i0 = blockIdx.y * 128;
    const int j0 = blockIdx.x * 128;
    const int row0 = (wid & 1) * 64 + (lane & 7) * 8;
    const int col0 = (wid >> 1) * 64 + ((lane >> 3) & 7) * 8;

    float acc[8][8] = {};

    for (int chunk = 0; chunk < 2; ++chunk){
        const int kb = chunk * 28;
        if (chunk) __syncthreads();            // all waves done reading chunk 0
        for (int v = tid; v < 28 * 32; v += 256){
            int kk = v >> 5, c4 = (v & 31) << 2;
            *(float4*)&As[kk][c4] = *(const float4*)&At[(size_t)(kb + kk) * NDET + i0 + c4];
            *(float4*)&Bs[kk][c4] = *(const float4*)&Bt[(size_t)(kb + kk) * NDET + j0 + c4];
        }
        __syncthreads();

        // software-pipelined inner loop: frag(kk+1) loads overlap frag(kk) FMAs
        float4 a0 = *(float4*)&As[0][row0];
        float4 a1 = *(float4*)&As[0][row0 + 4];
        float4 b0 = *(float4*)&Bs[0][col0];
        float4 b1 = *(float4*)&Bs[0][col0 + 4];
        #pragma unroll 4
        for (int kk = 0; kk < 28; ++kk){
            float4 na0, na1, nb0, nb1;
            if (kk < 27){
                na0 = *(float4*)&As[kk + 1][row0];
                na1 = *(float4*)&As[kk + 1][row0 + 4];
                nb0 = *(float4*)&Bs[kk + 1][col0];
                nb1 = *(float4*)&Bs[kk + 1][col0 + 4];
            }
            float a[8]  = {a0.x, a0.y, a0.z, a0.w, a1.x, a1.y, a1.z, a1.w};
            float bb[8] = {b0.x, b0.y, b0.z, b0.w, b1.x, b1.y, b1.z, b1.w};
            #pragma unroll
            for (int r = 0; r < 8; ++r)
                #pragma unroll
                for (int c = 0; c < 8; ++c)
                    acc[r][c] = fmaf(a[r], bb[c], acc[r][c]);
            if (kk < 27){ a0 = na0; a1 = na1; b0 = nb0; b1 = nb1; }
        }
    }

    const float inv_denom =
        (float)(1.0 / ((5.2915026221291814 + 1e-6) * (5.2915026221291814 + 1e-6)));

    #pragma unroll
    for (int r = 0; r < 8; ++r){
        const int i = i0 + row0 + r;
        float vals[8];
        #pragma unroll
        for (int c = 0; c < 8; ++c) vals[c] = acc[r][c] * inv_denom;

        *(float4*)&sim_out[(size_t)i * NDET + j0 + col0]     =
            make_float4(vals[0], vals[1], vals[2], vals[3]);
        *(float4*)&sim_out[(size_t)i * NDET + j0 + col0 + 4] =
            make_float4(vals[4], vals[5], vals[6], vals[7]);

        // local argmax, first-index-wins on ties (strict >, ascending scan)
        float bv = vals[0]; int bj = j0 + col0;
        #pragma unroll
        for (int c = 1; c < 8; ++c)
            if (vals[c] > bv){ bv = vals[c]; bj = j0 + col0 + c; }
        unsigned long long key =
            ((unsigned long long)f2sort(bv) << 32) | (unsigned)(NDET - 1 - bj);
        #pragma unroll
        for (int m = 8; m <= 32; m <<= 1){
            unsigned long long o = __shfl_xor(key, m);
            if (o > key) key = o;
        }
        if (((lane >> 3) & 7) == 0) atomicMax(&rowmax[i], key);
    }
}

// ---------------------------------------------------------------------------
// Fused greedy match: single block, colwin in LDS. Winner of column j =
// claimant with max (max_sim, -row) — scan-order semantics of the reference.
// ---------------------------------------------------------------------------
__global__ __launch_bounds__(1024) void match_kernel(
    const unsigned long long* __restrict__ rowmax,
    float* __restrict__ matches)
{
    __shared__ unsigned long long colwin[NDET];   // 32 KiB
    const int tid = threadIdx.x;
    for (int j = tid; j < NDET; j += 1024) colwin[j] = 0ull;
    __syncthreads();
    for (int i = tid; i < NDET; i += 1024){
        unsigned long long key = rowmax[i];
        unsigned hi = (unsigned)(key >> 32);
        float v = sort2f(hi);
        if (v > 0.3f){
            int j = NDET - 1 - (int)(key & 0xffffffffu);
            unsigned long long ck =
                ((unsigned long long)hi << 32) | (unsigned)(NDET - 1 - i);
            atomicMax(&colwin[j], ck);
        }
    }
    __syncthreads();
    for (int i = tid; i < NDET; i += 1024){
        unsigned long long key = rowmax[i];
        unsigned hi = (unsigned)(key >> 32);
        float v = sort2f(hi);
        int j = NDET - 1 - (int)(key & 0xffffffffu);
        unsigned long long ck =
            ((unsigned long long)hi << 32) | (unsigned)(NDET - 1 - i);
        matches[i] = (v > 0.3f && colwin[j] == ck) ? (float)j : -1.0f;
    }
}

// ---------------------------------------------------------------------------
extern "C" void kernel_launch(void* const* d_in, const int* in_sizes, int n_in,
                              void* d_out, int out_size, void* d_ws, size_t ws_size,
                              hipStream_t stream)
{
    const float* det_t  = (const float*)d_in[0];
    const float* det_t1 = (const float*)d_in[1];
    const float* Wp1 = (const float*)d_in[2];
    const float* bp1 = (const float*)d_in[3];
    const float* Wp2 = (const float*)d_in[4];
    const float* bp2 = (const float*)d_in[5];
    const float* Wa1 = (const float*)d_in[6];
    const float* ba1 = (const float*)d_in[7];
    const float* Wa2 = (const float*)d_in[8];
    const float* ba2 = (const float*)d_in[9];

    float* out     = (float*)d_out;
    float* matches = out;            // 4096 elements (written as float)
    float* sim     = out + NDET;     // 4096*4096

    char* ws = (char*)d_ws;
    unsigned long long* rowmax = (unsigned long long*)ws;                 // 32 KiB
    float* At = (float*)(ws + 32768);                                     // 56*4096 f32
    float* Bt = At + KDIM * NDET;

    hipMemsetAsync(rowmax, 0, 32768, stream);

    encode_kernel<<<1024, 256, 0, stream>>>(
        det_t, det_t1, Wp1, bp1, Wp2, bp2, Wa1, ba1, Wa2, ba2, At, Bt);

    sim_kernel<<<dim3(NDET / 128, NDET / 128), 256, 0, stream>>>(At, Bt, sim, rowmax);

    match_kernel<<<1, 1024, 0, stream>>>(rowmax, matches);
}

// Round 4
// 158.553 us; speedup vs baseline: 1.7562x; 1.7562x over previous
//
#include <hip/hip_runtime.h>
#include <math.h>

#define NDET 4096
#define DIM  128
#define HID  64
#define NOSC 28
#define KDIM 56   // 28 cos + 28 sin

constexpr float TWO_PI_F = 6.28318530717958647692f;

__device__ __forceinline__ unsigned f2sort(float f){
    unsigned u = __float_as_uint(f);
    return (u & 0x80000000u) ? ~u : (u | 0x80000000u);
}
__device__ __forceinline__ float sort2f(unsigned u){
    return __uint_as_float((u & 0x80000000u) ? (u & 0x7fffffffu) : ~u);
}
// broadcast lane t's value to all lanes (VALU pipe, no LDS)
__device__ __forceinline__ float lane_bcast(float v, int t){
    return __uint_as_float(__builtin_amdgcn_readlane(__float_as_uint(v), t));
}

// ---------------------------------------------------------------------------
// Encode: 2 rows per 64-lane wave, 4 waves/block, 1024 blocks (16 waves/CU).
// x via wave-uniform scalar loads; phase+amp nets fused in one d-loop (shared
// x loads, 4 independent FMA chains). Oscillators packed: lanes 0..31 = row0,
// lanes 32..63 = row1. Blocks 0..511 -> t (evolve, At); 512..1023 -> t1 (Bt).
// Outputs K-major: At[k][i], k: 0..27 cos, 28..55 sin.
// ---------------------------------------------------------------------------
__global__ __launch_bounds__(256) void encode_kernel(
    const float* __restrict__ det_t, const float* __restrict__ det_t1,
    const float* __restrict__ Wp1, const float* __restrict__ bp1,
    const float* __restrict__ Wp2, const float* __restrict__ bp2,
    const float* __restrict__ Wa1, const float* __restrict__ ba1,
    const float* __restrict__ Wa2, const float* __restrict__ ba2,
    float* __restrict__ At, float* __restrict__ Bt)
{
    const int tid  = threadIdx.x;
    const int lane = tid & 63;
    const int wv   = tid >> 6;
    const int b    = blockIdx.x;
    const bool isT = b < 512;
    const int lr = __builtin_amdgcn_readfirstlane(((b & 511) << 3) + wv * 2);
    const float* __restrict__ src = (isT ? det_t : det_t1) + (size_t)lr * DIM;

    // ---- layer 1: phase (+amp for t rows), fused over d ----
    float h0 = bp1[lane], h1 = h0;
    float g0 = 0.0f, g1 = 0.0f;
    if (isT){
        g0 = ba1[lane]; g1 = g0;
        #pragma unroll 8
        for (int d = 0; d < DIM; ++d){
            float x0 = src[d], x1 = src[DIM + d];   // wave-uniform -> s_load
            float wp = Wp1[d * HID + lane];
            float wa = Wa1[d * HID + lane];
            h0 = fmaf(x0, wp, h0);  h1 = fmaf(x1, wp, h1);
            g0 = fmaf(x0, wa, g0);  g1 = fmaf(x1, wa, g1);
        }
        g0 = fmaxf(g0, 0.0f); g1 = fmaxf(g1, 0.0f);
    } else {
        #pragma unroll 8
        for (int d = 0; d < DIM; ++d){
            float x0 = src[d], x1 = src[DIM + d];
            float wp = Wp1[d * HID + lane];
            h0 = fmaf(x0, wp, h0);  h1 = fmaf(x1, wp, h1);
        }
    }
    h0 = fmaxf(h0, 0.0f); h1 = fmaxf(h1, 0.0f);

    // ---- layer 2: oscillator k = lane&31 (valid < 28); both rows parallel ----
    const int k  = lane & 31;
    const bool kv = k < NOSC;
    const int kc = kv ? k : 0;

    float pa = bp2[kc], pb = pa;
    #pragma unroll 16
    for (int t = 0; t < HID; ++t){
        float w2 = Wp2[t * NOSC + kc];          // 7KB, L1-hot
        pa = fmaf(lane_bcast(h0, t), w2, pa);
        pb = fmaf(lane_bcast(h1, t), w2, pb);
    }
    float aa = 0.0f, ab = 0.0f;
    if (isT){
        aa = ba2[kc]; ab = aa;
        #pragma unroll 16
        for (int t = 0; t < HID; ++t){
            float w2 = Wa2[t * NOSC + kc];
            aa = fmaf(lane_bcast(g0, t), w2, aa);
            ab = fmaf(lane_bcast(g1, t), w2, ab);
        }
    }

    const bool hiHalf = lane >= 32;
    float p2 = hiHalf ? pb : pa;
    float ph = fmodf(p2, TWO_PI_F);
    if (ph < 0.0f) ph += TWO_PI_F;               // python-style mod, [0, 2pi)

    // ---- Kuramoto evolve (t rows only); butterfly within each 32-lane half ----
    if (isT){
        float a2 = hiHalf ? ab : aa;
        float am = fmaxf(a2, 0.0f) + log1pf(expf(-fabsf(a2)));   // stable softplus
        const float omega = TWO_PI_F * ((k < 4) ? 2.0f : (k < 12) ? 6.0f : 40.0f);
        for (int s5 = 0; s5 < 5; ++s5){
            float sn, cs;
            sincosf(ph, &sn, &cs);
            float c = kv ? cs : 0.0f;
            float s = kv ? sn : 0.0f;
            float sc = c, ss = s;
            sc += __shfl_xor(sc, 16); ss += __shfl_xor(ss, 16);
            sc += __shfl_xor(sc,  8); ss += __shfl_xor(ss,  8);
            sc += __shfl_xor(sc,  4); ss += __shfl_xor(ss,  4);
            sc += __shfl_xor(sc,  2); ss += __shfl_xor(ss,  2);
            sc += __shfl_xor(sc,  1); ss += __shfl_xor(ss,  1);
            float mc = sc * (1.0f / NOSC);
            float ms = ss * (1.0f / NOSC);
            float coupling = ms * c - mc * s;
            ph += 0.01f * (omega + am * coupling);
            ph = fmodf(ph, TWO_PI_F);
            if (ph < 0.0f) ph += TWO_PI_F;
        }
    }

    if (kv){
        const int row = lr + (hiHalf ? 1 : 0);
        float sn, cs;
        sincosf(ph, &sn, &cs);
        float* __restrict__ dst = isT ? At : Bt;
        dst[k * NDET + row]          = cs;
        dst[(NOSC + k) * NDET + row] = sn;
    }
}

// ---------------------------------------------------------------------------
// Sim GEMM: 128x128 tile / block, 256 threads, 8x8 micro-tile, K in 2x28
// chunks (28.7KB LDS). Round-2 body (NO prefetch — it spilled to scratch under
// the 128-reg cap in round 3). __launch_bounds__(256,4): unified VGPR+AGPR cap
// 128 -> 4 waves/SIMD; body needs ~105 regs so it fits without scratch.
// Fused per-row argmax -> atomicMax packed key.
// ---------------------------------------------------------------------------
__global__ __launch_bounds__(256, 4) void sim_kernel(
    const float* __restrict__ At, const float* __restrict__ Bt,
    float* __restrict__ sim_out, unsigned long long* __restrict__ rowmax)
{
    __shared__ float As[28][128];
    __shared__ float Bs[28][128];

    const int tid  = threadIdx.x;
    const int lane = tid & 63;
    const int wid  = tid >> 6;
    const int i0 = blockIdx.y * 128;
    const int j0 = blockIdx.x * 128;
    const int row0 = (wid & 1) * 64 + (lane & 7) * 8;
    const int col0 = (wid >> 1) * 64 + ((lane >> 3) & 7) * 8;

    float acc[8][8] = {};

    for (int chunk = 0; chunk < 2; ++chunk){
        const int kb = chunk * 28;
        if (chunk) __syncthreads();            // all waves done reading chunk 0
        for (int v = tid; v < 28 * 32; v += 256){
            int kk = v >> 5, c4 = (v & 31) << 2;
            *(float4*)&As[kk][c4] = *(const float4*)&At[(size_t)(kb + kk) * NDET + i0 + c4];
            *(float4*)&Bs[kk][c4] = *(const float4*)&Bt[(size_t)(kb + kk) * NDET + j0 + c4];
        }
        __syncthreads();

        #pragma unroll 4
        for (int kk = 0; kk < 28; ++kk){
            float4 a0 = *(float4*)&As[kk][row0];
            float4 a1 = *(float4*)&As[kk][row0 + 4];
            float4 b0 = *(float4*)&Bs[kk][col0];
            float4 b1 = *(float4*)&Bs[kk][col0 + 4];
            float a[8]  = {a0.x, a0.y, a0.z, a0.w, a1.x, a1.y, a1.z, a1.w};
            float bb[8] = {b0.x, b0.y, b0.z, b0.w, b1.x, b1.y, b1.z, b1.w};
            #pragma unroll
            for (int r = 0; r < 8; ++r)
                #pragma unroll
                for (int c = 0; c < 8; ++c)
                    acc[r][c] = fmaf(a[r], bb[c], acc[r][c]);
        }
    }

    const float inv_denom =
        (float)(1.0 / ((5.2915026221291814 + 1e-6) * (5.2915026221291814 + 1e-6)));

    #pragma unroll
    for (int r = 0; r < 8; ++r){
        const int i = i0 + row0 + r;
        float vals[8];
        #pragma unroll
        for (int c = 0; c < 8; ++c) vals[c] = acc[r][c] * inv_denom;

        *(float4*)&sim_out[(size_t)i * NDET + j0 + col0]     =
            make_float4(vals[0], vals[1], vals[2], vals[3]);
        *(float4*)&sim_out[(size_t)i * NDET + j0 + col0 + 4] =
            make_float4(vals[4], vals[5], vals[6], vals[7]);

        // local argmax, first-index-wins on ties (strict >, ascending scan)
        float bv = vals[0]; int bj = j0 + col0;
        #pragma unroll
        for (int c = 1; c < 8; ++c)
            if (vals[c] > bv){ bv = vals[c]; bj = j0 + col0 + c; }
        unsigned long long key =
            ((unsigned long long)f2sort(bv) << 32) | (unsigned)(NDET - 1 - bj);
        #pragma unroll
        for (int m = 8; m <= 32; m <<= 1){
            unsigned long long o = __shfl_xor(key, m);
            if (o > key) key = o;
        }
        if (((lane >> 3) & 7) == 0) atomicMax(&rowmax[i], key);
    }
}

// ---------------------------------------------------------------------------
// Greedy match via per-column claims. Winner of column j = claimant with max
// (max_sim, -row) — exactly the scan-order semantics of the reference.
// ---------------------------------------------------------------------------
__global__ __launch_bounds__(256) void claim_kernel(
    const unsigned long long* __restrict__ rowmax,
    unsigned long long* __restrict__ colwin)
{
    int i = blockIdx.x * 256 + threadIdx.x;
    if (i >= NDET) return;
    unsigned long long key = rowmax[i];
    unsigned hi = (unsigned)(key >> 32);
    float v = sort2f(hi);
    if (v > 0.3f){
        int j = NDET - 1 - (int)(key & 0xffffffffu);
        unsigned long long ck = ((unsigned long long)hi << 32) | (unsigned)(NDET - 1 - i);
        atomicMax(&colwin[j], ck);
    }
}

__global__ __launch_bounds__(256) void finalize_kernel(
    const unsigned long long* __restrict__ rowmax,
    const unsigned long long* __restrict__ colwin,
    float* __restrict__ matches)
{
    int i = blockIdx.x * 256 + threadIdx.x;
    if (i >= NDET) return;
    unsigned long long key = rowmax[i];
    unsigned hi = (unsigned)(key >> 32);
    float v = sort2f(hi);
    int j = NDET - 1 - (int)(key & 0xffffffffu);
    unsigned long long ck = ((unsigned long long)hi << 32) | (unsigned)(NDET - 1 - i);
    bool ok = (v > 0.3f) && (colwin[j] == ck);
    matches[i] = ok ? (float)j : -1.0f;
}

// ---------------------------------------------------------------------------
extern "C" void kernel_launch(void* const* d_in, const int* in_sizes, int n_in,
                              void* d_out, int out_size, void* d_ws, size_t ws_size,
                              hipStream_t stream)
{
    const float* det_t  = (const float*)d_in[0];
    const float* det_t1 = (const float*)d_in[1];
    const float* Wp1 = (const float*)d_in[2];
    const float* bp1 = (const float*)d_in[3];
    const float* Wp2 = (const float*)d_in[4];
    const float* bp2 = (const float*)d_in[5];
    const float* Wa1 = (const float*)d_in[6];
    const float* ba1 = (const float*)d_in[7];
    const float* Wa2 = (const float*)d_in[8];
    const float* ba2 = (const float*)d_in[9];

    float* out     = (float*)d_out;
    float* matches = out;            // 4096 elements (written as float)
    float* sim     = out + NDET;     // 4096*4096

    char* ws = (char*)d_ws;
    unsigned long long* rowmax = (unsigned long long*)ws;                 // 32 KiB
    unsigned long long* colwin = (unsigned long long*)(ws + 32768);       // 32 KiB
    float* At = (float*)(ws + 65536);                                     // 56*4096 f32
    float* Bt = At + KDIM * NDET;

    hipMemsetAsync(d_ws, 0, 65536, stream);  // zero rowmax + colwin

    encode_kernel<<<1024, 256, 0, stream>>>(
        det_t, det_t1, Wp1, bp1, Wp2, bp2, Wa1, ba1, Wa2, ba2, At, Bt);

    sim_kernel<<<dim3(NDET / 128, NDET / 128), 256, 0, stream>>>(At, Bt, sim, rowmax);

    claim_kernel<<<NDET / 256, 256, 0, stream>>>(rowmax, colwin);
    finalize_kernel<<<NDET / 256, 256, 0, stream>>>(rowmax, colwin, matches);
}